// Round 3
// baseline (941.151 us; speedup 1.0000x reference)
//
#include <hip/hip_runtime.h>
#include <hip/hip_bf16.h>
#include <stdint.h>
#include <math.h>

typedef unsigned short u16;
typedef unsigned int u32;
typedef __bf16 v8bf __attribute__((ext_vector_type(8)));
typedef float v4f __attribute__((ext_vector_type(4)));

constexpr int BATCH = 2;
constexpr int SEQ = 2048;
constexpr int HID = 1024;
constexpr int NHEAD = 16;
constexpr int HDIM = 64;
constexpr int MROWS = BATCH * SEQ;          // 4096
constexpr int QKV_LD = 3 * HID;             // 3072
constexpr int BIAS_LD = 2 * 1024 + 1;       // 2049
constexpr size_t BIAS_HSTRIDE = (size_t)BIAS_LD * BIAS_LD;

// 16B payload, 4B-aligned (bias rows have stride 2049 floats -> not 16B aligned)
struct f4u { float v[4]; };

__device__ __forceinline__ u16 f2bf(float f) {
    u32 u = __builtin_bit_cast(u32, f);
    u32 r = u + 0x7fffu + ((u >> 16) & 1u);   // RNE
    return (u16)(r >> 16);
}
__device__ __forceinline__ u16 f2bf_fast(float f) {  // round-to-nearest (no tie fix) — P weights only
    return (u16)((__builtin_bit_cast(u32, f) + 0x8000u) >> 16);
}
__device__ __forceinline__ float bf2f(u16 h) {
    return __builtin_bit_cast(float, (u32)h << 16);
}

// async global->LDS, 16B per lane. LDS dst = wave-uniform base + lane*16.
__device__ __forceinline__ void gld16(const void* g, void* lds_base) {
    __builtin_amdgcn_global_load_lds(
        (const __attribute__((address_space(1))) u32*)(uintptr_t)g,
        (__attribute__((address_space(3))) u32*)(u32)(uintptr_t)lds_base,
        16, 0, 0);
}

// swizzled LDS chunk offsets (16B chunks): position c in row r holds chunk c^(r&mask)
__device__ __forceinline__ int swoff8(int row, int chunk)  { return (row * 8  + (chunk ^ (row & 7)))  << 4; }

__device__ __forceinline__ float2 blockreduce2(float a, float b) {
    #pragma unroll
    for (int m = 1; m < 64; m <<= 1) {
        a += __shfl_xor(a, m, 64);
        b += __shfl_xor(b, m, 64);
    }
    __shared__ float la[4], lb[4];
    int w = threadIdx.x >> 6;
    if ((threadIdx.x & 63) == 0) { la[w] = a; lb[w] = b; }
    __syncthreads();
    a = la[0] + la[1] + la[2] + la[3];
    b = lb[0] + lb[1] + lb[2] + lb[3];
    __syncthreads();
    return make_float2(a, b);
}

// ---------------- weight transpose + fp32 -> bf16 (scaled):  W[K,N] -> Wt[N,K] ----------------
__global__ __launch_bounds__(256) void k_wt(const float* __restrict__ W, u16* __restrict__ Wt,
                                            int K, int N, float scale) {
    __shared__ float t[32][33];
    int n0 = blockIdx.x * 32, k0 = blockIdx.y * 32;
    int tx = threadIdx.x & 31, ty = threadIdx.x >> 5;  // 32 x 8
    #pragma unroll
    for (int i = 0; i < 32; i += 8) t[ty + i][tx] = W[(size_t)(k0 + ty + i) * N + n0 + tx];
    __syncthreads();
    #pragma unroll
    for (int i = 0; i < 32; i += 8) Wt[(size_t)(n0 + ty + i) * K + k0 + tx] = f2bf(t[tx][ty + i] * scale);
}

// ---------------- concat bias for fused QKV (q scaled by 1/8) ----------------
__global__ __launch_bounds__(256) void k_bcat(const float* __restrict__ bq, const float* __restrict__ bk,
                                              const float* __restrict__ bv, float* __restrict__ o) {
    int n = blockIdx.x * 256 + threadIdx.x;
    float v = (n < 1024) ? bq[n] * 0.125f : (n < 2048 ? bk[n - 1024] : bv[n - 2048]);
    o[n] = v;
}

// ---------------- pe (Linear(1->H)+LN) + add + LN -> x (bf16) ----------------
__global__ __launch_bounds__(256) void k_prenorm(const float* __restrict__ hidden,
        const float* __restrict__ pe_w, const float* __restrict__ pe_b,
        const float* __restrict__ pe_g, const float* __restrict__ pe_beta,
        const float* __restrict__ ng, const float* __restrict__ nb, u16* __restrict__ xbf) {
    int row = blockIdx.x;                 // b*SEQ + s
    int s = row & (SEQ - 1);
    float pos = ((float)s - 1024.0f) * (1.0f / 1024.0f);
    int t = threadIdx.x, hh = t * 4;
    float4 pw = *(const float4*)(pe_w + hh);
    float4 pb = *(const float4*)(pe_b + hh);
    float v[4] = { pos * pw.x + pb.x, pos * pw.y + pb.y, pos * pw.z + pb.z, pos * pw.w + pb.w };
    float s1 = 0.f, s2 = 0.f;
    #pragma unroll
    for (int i = 0; i < 4; i++) { s1 += v[i]; s2 += v[i] * v[i]; }
    float2 red = blockreduce2(s1, s2);
    float mean = red.x * (1.f / HID);
    float var  = red.y * (1.f / HID) - mean * mean;
    float rstd = rsqrtf(var + 1e-5f);
    float4 pg = *(const float4*)(pe_g + hh);
    float4 pbe = *(const float4*)(pe_beta + hh);
    float4 hv = *(const float4*)(hidden + (size_t)row * HID + hh);
    v[0] = hv.x + (v[0] - mean) * rstd * pg.x + pbe.x;
    v[1] = hv.y + (v[1] - mean) * rstd * pg.y + pbe.y;
    v[2] = hv.z + (v[2] - mean) * rstd * pg.z + pbe.z;
    v[3] = hv.w + (v[3] - mean) * rstd * pg.w + pbe.w;
    s1 = 0.f; s2 = 0.f;
    #pragma unroll
    for (int i = 0; i < 4; i++) { s1 += v[i]; s2 += v[i] * v[i]; }
    red = blockreduce2(s1, s2);
    mean = red.x * (1.f / HID);
    var  = red.y * (1.f / HID) - mean * mean;
    rstd = rsqrtf(var + 1e-5f);
    float4 gg = *(const float4*)(ng + hh);
    float4 bb = *(const float4*)(nb + hh);
    ushort4 o;
    o.x = f2bf((v[0] - mean) * rstd * gg.x + bb.x);
    o.y = f2bf((v[1] - mean) * rstd * gg.y + bb.y);
    o.z = f2bf((v[2] - mean) * rstd * gg.z + bb.z);
    o.w = f2bf((v[3] - mean) * rstd * gg.w + bb.w);
    *(ushort4*)(xbf + (size_t)row * HID + hh) = o;
}

// ---------------- LN + ReLU: bf16 [rows][2048] -> bf16, 8 elems/thread ----------------
__global__ __launch_bounds__(256) void k_ln_relu(const u16* __restrict__ Z,
        const float* __restrict__ g, const float* __restrict__ be, u16* __restrict__ Y) {
    const int N = 2048;
    int row = blockIdx.x, t = threadIdx.x, base = t * 8;
    union { uint4 q; u16 h[8]; } u;
    u.q = *(const uint4*)(Z + (size_t)row * N + base);
    float v[8];
    float s1 = 0.f, s2 = 0.f;
    #pragma unroll
    for (int i = 0; i < 8; i++) { v[i] = bf2f(u.h[i]); s1 += v[i]; s2 += v[i] * v[i]; }
    float2 red = blockreduce2(s1, s2);
    float mean = red.x * (1.f / N);
    float var  = red.y * (1.f / N) - mean * mean;
    float rstd = rsqrtf(var + 1e-5f);
    float4 g0 = *(const float4*)(g + base), g1 = *(const float4*)(g + base + 4);
    float4 b0 = *(const float4*)(be + base), b1 = *(const float4*)(be + base + 4);
    float gg[8] = { g0.x, g0.y, g0.z, g0.w, g1.x, g1.y, g1.z, g1.w };
    float bb[8] = { b0.x, b0.y, b0.z, b0.w, b1.x, b1.y, b1.z, b1.w };
    union { uint4 q; u16 h[8]; } o;
    #pragma unroll
    for (int i = 0; i < 8; i++) o.h[i] = f2bf(fmaxf((v[i] - mean) * rstd * gg[i] + bb[i], 0.f));
    *(uint4*)(Y + (size_t)row * N + base) = o.q;
}

// ---------------- V transpose: qkv[b*S][3072] (V block) -> [b][h][d][S] (bf16) ----------------
__global__ __launch_bounds__(256) void k_vtrans(const u16* __restrict__ QKV, u16* __restrict__ Vt) {
    __shared__ u16 t[64][68];
    int s0 = blockIdx.x * 64, h = blockIdx.y, b = blockIdx.z;
    int x = threadIdx.x & 63, y = threadIdx.x >> 6;
    #pragma unroll
    for (int i = 0; i < 64; i += 4) {
        int r = i + y;
        t[r][x] = QKV[(size_t)(b * SEQ + s0 + r) * QKV_LD + 2048 + h * HDIM + x];
    }
    __syncthreads();
    size_t ob = (size_t)(b * NHEAD + h) * HDIM;
    #pragma unroll
    for (int i = 0; i < 64; i += 4) {
        int d = i + y;
        Vt[(ob + d) * SEQ + s0 + x] = t[x][d];
    }
}

// ---------------- bf16 MFMA GEMM: C[M,N] = A[M,K] @ Bt[N,K]^T + bias ----------------
// 128x128 tile, BK=64, async global_load_lds staging (swizzle-inverted lane addressing).
template <int OUT_BF16>
__global__ __launch_bounds__(256, 3) void k_gemm(const u16* __restrict__ A, const u16* __restrict__ Bt,
        const float* __restrict__ bias, void* __restrict__ C, int N, int K) {
    __shared__ __align__(16) u16 lA[128 * 64];
    __shared__ __align__(16) u16 lB[128 * 64];
    char* lAc = (char*)lA;
    char* lBc = (char*)lB;
    const int m0 = blockIdx.x * 128, n0 = blockIdx.y * 128;
    const int tid = threadIdx.x, wave = tid >> 6, lane = tid & 63;
    const int wr = wave >> 1, wc = wave & 1, q4 = lane >> 4, ml = lane & 15;
    const int srow = wave * 8 + (lane >> 3);
    const int sqc  = (lane & 7) ^ (lane >> 3);

    v4f acc[4][4];
    v4f zz = {0.f, 0.f, 0.f, 0.f};
    #pragma unroll
    for (int i = 0; i < 4; i++)
        #pragma unroll
        for (int j = 0; j < 4; j++) acc[i][j] = zz;

    for (int k0 = 0; k0 < K; k0 += 64) {
        __syncthreads();
        #pragma unroll
        for (int it = 0; it < 4; it++) {
            int r = it * 32 + srow;
            gld16(A  + (size_t)(m0 + r) * K + k0 + sqc * 8, lAc + (it * 32 + wave * 8) * 128);
            gld16(Bt + (size_t)(n0 + r) * K + k0 + sqc * 8, lBc + (it * 32 + wave * 8) * 128);
        }
        __syncthreads();
        #pragma unroll
        for (int kk = 0; kk < 2; kk++) {
            v8bf af[4], bfv[4];
            #pragma unroll
            for (int i = 0; i < 4; i++) af[i] = *(const v8bf*)(lAc + swoff8(wr * 64 + i * 16 + ml, kk * 4 + q4));
            #pragma unroll
            for (int j = 0; j < 4; j++) bfv[j] = *(const v8bf*)(lBc + swoff8(wc * 64 + j * 16 + ml, kk * 4 + q4));
            #pragma unroll
            for (int i = 0; i < 4; i++)
                #pragma unroll
                for (int j = 0; j < 4; j++)
                    acc[i][j] = __builtin_amdgcn_mfma_f32_16x16x32_bf16(af[i], bfv[j], acc[i][j], 0, 0, 0);
        }
    }
    #pragma unroll
    for (int i = 0; i < 4; i++) {
        int rb = m0 + wr * 64 + i * 16 + q4 * 4;
        #pragma unroll
        for (int j = 0; j < 4; j++) {
            int col = n0 + wc * 64 + j * 16 + ml;
            float bv = bias[col];
            #pragma unroll
            for (int r = 0; r < 4; r++) {
                float val = acc[i][j][r] + bv;
                if (OUT_BF16) ((u16*)C)[(size_t)(rb + r) * N + col] = f2bf(val);
                else          ((float*)C)[(size_t)(rb + r) * N + col] = val;
            }
        }
    }
}

// ---------------- flash attention, S^T formulation ----------------
// S^T = K·Q^T so k is register-minor in the C-layout: bias loads vectorize to dwordx4,
// K/V/Q fragments come straight from global (L2-hot), no __syncthreads in the kt loop.
// grid (b=2, qt=32, h=16), block 256 = 4 independent waves, 16 q-rows/wave, k-tile 64.
__global__ __launch_bounds__(256, 4) void k_attn(const u16* __restrict__ QKV,
        const u16* __restrict__ Vtm, const float* __restrict__ bias, u16* __restrict__ ctx) {
    // per-wave P^T buffer: 16 q-rows x 64 k, row stride 72 u16 (144B) -> optimal bank phasing
    __shared__ __align__(16) u16 lP[4][16 * 72];
    const int b = blockIdx.x, qt = blockIdx.y, h = blockIdx.z;
    const int tid = threadIdx.x, wave = tid >> 6, lane = tid & 63;
    const int q4 = lane >> 4, ml = lane & 15;
    char* lPc = (char*)lP[wave];
    const int qbase = qt * 64 + wave * 16;

    const u16* Qb = QKV + (size_t)(b * SEQ) * QKV_LD + h * HDIM;
    const u16* Kb = QKV + (size_t)(b * SEQ) * QKV_LD + 1024 + h * HDIM;
    const u16* Vb = Vtm + (size_t)(b * NHEAD + h) * HDIM * SEQ;
    const float* brow = bias + (size_t)h * BIAS_HSTRIDE + (size_t)(qbase + ml) * BIAS_LD;

    // Q as B-fragments: lane holds Q[q=ml][d = d0*32 + q4*8 .. +8]
    v8bf qf[2];
    #pragma unroll
    for (int d0 = 0; d0 < 2; d0++)
        qf[d0] = *(const v8bf*)(Qb + (size_t)(qbase + ml) * QKV_LD + d0 * 32 + q4 * 8);

    float mr = -1e30f, lr = 0.f;           // per q=ml (replicated over q4)
    v4f o[4];                               // O^T: 4 d-tiles, col q=ml, rows d=q4*4+r
    v4f zz = {0.f, 0.f, 0.f, 0.f};
    #pragma unroll
    for (int n = 0; n < 4; n++) o[n] = zz;

    // bias prefetch for kt=0: lane covers k = j*16 + q4*4 .. +4 (16B, 4B-aligned)
    f4u bv[4];
    #pragma unroll
    for (int j = 0; j < 4; j++) bv[j] = *(const f4u*)(brow + j * 16 + q4 * 4);

    const int lpw = ml * 144;   // lane's P row base (bytes)

    for (int kt = 0; kt < SEQ / 64; ++kt) {
        const int k0 = kt * 64;
        // S^T = K·Q^T : 4 k-tiles of 16, kdim 64 in 2 MFMAs
        v4f sa[4];
        #pragma unroll
        for (int jt = 0; jt < 4; jt++) {
            v8bf kf0 = *(const v8bf*)(Kb + (size_t)(k0 + jt * 16 + ml) * QKV_LD + q4 * 8);
            v8bf kf1 = *(const v8bf*)(Kb + (size_t)(k0 + jt * 16 + ml) * QKV_LD + 32 + q4 * 8);
            sa[jt] = __builtin_amdgcn_mfma_f32_16x16x32_bf16(kf0, qf[0], zz, 0, 0, 0);
            sa[jt] = __builtin_amdgcn_mfma_f32_16x16x32_bf16(kf1, qf[1], sa[jt], 0, 0, 0);
        }
        // prefetch next k-tile's bias while MFMA/softmax run
        f4u bn[4];
        if (kt < SEQ / 64 - 1) {
            #pragma unroll
            for (int j = 0; j < 4; j++) bn[j] = *(const f4u*)(brow + k0 + 64 + j * 16 + q4 * 4);
        }
        // bias add + online softmax (k lives in regs r and q4 groups)
        float mx = -1e30f;
        #pragma unroll
        for (int j = 0; j < 4; j++)
            #pragma unroll
            for (int r = 0; r < 4; r++) { sa[j][r] += bv[j].v[r]; mx = fmaxf(mx, sa[j][r]); }
        mx = fmaxf(mx, __shfl_xor(mx, 16, 64));
        mx = fmaxf(mx, __shfl_xor(mx, 32, 64));
        float mnew = fmaxf(mr, mx);
        float alpha = __expf(mr - mnew);
        mr = mnew;
        float rs = 0.f;
        #pragma unroll
        for (int j = 0; j < 4; j++)
            #pragma unroll
            for (int r = 0; r < 4; r++) {
                float p = __expf(sa[j][r] - mnew);
                sa[j][r] = p;
                rs += p;
            }
        rs += __shfl_xor(rs, 16, 64);
        rs += __shfl_xor(rs, 32, 64);
        lr = lr * alpha + rs;
        #pragma unroll
        for (int n = 0; n < 4; n++) o[n] *= alpha;
        // P^T -> LDS: lane writes 4 consecutive k (bf16) = one b64 per tile
        #pragma unroll
        for (int j = 0; j < 4; j++) {
            uint2 pk;
            pk.x = (u32)f2bf_fast(sa[j][0]) | ((u32)f2bf_fast(sa[j][1]) << 16);
            pk.y = (u32)f2bf_fast(sa[j][2]) | ((u32)f2bf_fast(sa[j][3]) << 16);
            *(uint2*)(lPc + lpw + j * 32 + q4 * 8) = pk;
        }
        // O^T += V^T · P^T  (A = V^T from global, B = P^T from LDS b128)
        #pragma unroll
        for (int step = 0; step < 2; step++) {
            v8bf pf = *(const v8bf*)(lPc + lpw + step * 64 + q4 * 16);
            #pragma unroll
            for (int n = 0; n < 4; n++) {
                v8bf vf = *(const v8bf*)(Vb + (size_t)(n * 16 + ml) * SEQ + k0 + step * 32 + q4 * 8);
                o[n] = __builtin_amdgcn_mfma_f32_16x16x32_bf16(vf, pf, o[n], 0, 0, 0);
            }
        }
        #pragma unroll
        for (int j = 0; j < 4; j++) bv[j] = bn[j];
    }
    // epilogue: O^T[d][q] / l -> ctx[q][h*64+d], 8B stores
    float inv = 1.0f / lr;
    size_t rowb = (size_t)(b * SEQ + qbase + ml) * HID + h * HDIM + q4 * 4;
    #pragma unroll
    for (int n = 0; n < 4; n++) {
        ushort4 st;
        st.x = f2bf(o[n][0] * inv);
        st.y = f2bf(o[n][1] * inv);
        st.z = f2bf(o[n][2] * inv);
        st.w = f2bf(o[n][3] * inv);
        *(ushort4*)(ctx + rowb + n * 16) = st;
    }
}

extern "C" void kernel_launch(void* const* d_in, const int* in_sizes, int n_in,
                              void* d_out, int out_size, void* d_ws, size_t ws_size,
                              hipStream_t stream) {
    const float* hidden = (const float*)d_in[0];
    const float* wbias  = (const float*)d_in[1];
    const float* pe_w   = (const float*)d_in[2];
    const float* pe_b   = (const float*)d_in[3];
    const float* pe_g   = (const float*)d_in[4];
    const float* pe_be  = (const float*)d_in[5];
    const float* ng     = (const float*)d_in[6];
    const float* nb     = (const float*)d_in[7];
    const float* Wq = (const float*)d_in[8];  const float* bq = (const float*)d_in[9];
    const float* Wk = (const float*)d_in[10]; const float* bk = (const float*)d_in[11];
    const float* Wv = (const float*)d_in[12]; const float* bv = (const float*)d_in[13];
    const float* W1 = (const float*)d_in[14]; const float* b1 = (const float*)d_in[15];
    const float* g1 = (const float*)d_in[16]; const float* be1 = (const float*)d_in[17];
    const float* W2 = (const float*)d_in[18]; const float* b2 = (const float*)d_in[19];
    const float* g2 = (const float*)d_in[20]; const float* be2 = (const float*)d_in[21];
    const float* W3 = (const float*)d_in[22]; const float* b3 = (const float*)d_in[23];
    const float* g3 = (const float*)d_in[24]; const float* be3 = (const float*)d_in[25];
    const float* W4 = (const float*)d_in[26]; const float* b4 = (const float*)d_in[27];

    char* ws = (char*)d_ws;
    size_t off = 0;
    auto alloc = [&](size_t bytes) {
        char* p = ws + off;
        off += (bytes + 1023) & ~(size_t)1023;
        return p;
    };
    u16* wqkvt = (u16*)alloc((size_t)3072 * 1024 * 2);
    u16* w1t = (u16*)alloc((size_t)2048 * 1024 * 2);
    u16* w2t = (u16*)alloc((size_t)2048 * 2048 * 2);
    u16* w3t = (u16*)alloc((size_t)2048 * 2048 * 2);
    u16* w4t = (u16*)alloc((size_t)1024 * 2048 * 2);
    float* bqkv = (float*)alloc((size_t)3072 * 4);
    u16* xbf = (u16*)alloc((size_t)MROWS * HID * 2);
    u16* qkv = (u16*)alloc((size_t)MROWS * QKV_LD * 2);
    u16* vtb = (u16*)alloc((size_t)MROWS * HID * 2);
    u16* ctx = (u16*)alloc((size_t)MROWS * HID * 2);
    u16* zb  = (u16*)alloc((size_t)MROWS * 2048 * 2);
    u16* ya  = (u16*)alloc((size_t)MROWS * 2048 * 2);
    u16* yb  = (u16*)alloc((size_t)MROWS * 2048 * 2);

    dim3 blk(256);
    // weight transposes (fp32 -> bf16 [N,K]); 1/8 attention scale folded into Wq
    k_wt<<<dim3(32, 32), blk, 0, stream>>>(Wq, wqkvt, 1024, 1024, 0.125f);
    k_wt<<<dim3(32, 32), blk, 0, stream>>>(Wk, wqkvt + (size_t)1024 * 1024, 1024, 1024, 1.0f);
    k_wt<<<dim3(32, 32), blk, 0, stream>>>(Wv, wqkvt + (size_t)2048 * 1024, 1024, 1024, 1.0f);
    k_wt<<<dim3(64, 32), blk, 0, stream>>>(W1, w1t, 1024, 2048, 1.0f);
    k_wt<<<dim3(64, 64), blk, 0, stream>>>(W2, w2t, 2048, 2048, 1.0f);
    k_wt<<<dim3(64, 64), blk, 0, stream>>>(W3, w3t, 2048, 2048, 1.0f);
    k_wt<<<dim3(32, 64), blk, 0, stream>>>(W4, w4t, 2048, 1024, 1.0f);
    k_bcat<<<dim3(12), blk, 0, stream>>>(bq, bk, bv, bqkv);
    // x = LN(hidden + LN(pos*pe_w + pe_b))
    k_prenorm<<<MROWS, blk, 0, stream>>>(hidden, pe_w, pe_b, pe_g, pe_be, ng, nb, xbf);
    // fused QKV projection -> qkv [4096][3072]
    k_gemm<1><<<dim3(32, 24), blk, 0, stream>>>(xbf, wqkvt, bqkv, qkv, QKV_LD, 1024);
    // V -> [b][h][d][s]
    k_vtrans<<<dim3(32, 16, 2), blk, 0, stream>>>(qkv, vtb);
    // fused attention
    k_attn<<<dim3(2, 32, 16), blk, 0, stream>>>(qkv, vtb, wbias, ctx);
    // out_proj MLP (bf16 intermediates)
    k_gemm<1><<<dim3(32, 16), blk, 0, stream>>>(ctx, w1t, b1, zb, 2048, 1024);
    k_ln_relu<<<MROWS, blk, 0, stream>>>(zb, g1, be1, ya);
    k_gemm<1><<<dim3(32, 16), blk, 0, stream>>>(ya, w2t, b2, zb, 2048, 2048);
    k_ln_relu<<<MROWS, blk, 0, stream>>>(zb, g2, be2, yb);
    k_gemm<1><<<dim3(32, 16), blk, 0, stream>>>(yb, w3t, b3, zb, 2048, 2048);
    k_ln_relu<<<MROWS, blk, 0, stream>>>(zb, g3, be3, ya);
    k_gemm<0><<<dim3(32, 8), blk, 0, stream>>>(ya, w4t, b4, (float*)d_out, 1024, 2048);
}

// Round 4
// 734.683 us; speedup vs baseline: 1.2810x; 1.2810x over previous
//
#include <hip/hip_runtime.h>
#include <hip/hip_bf16.h>
#include <stdint.h>
#include <math.h>

typedef unsigned short u16;
typedef unsigned int u32;
typedef __bf16 v8bf __attribute__((ext_vector_type(8)));
typedef float v4f __attribute__((ext_vector_type(4)));

constexpr int BATCH = 2;
constexpr int SEQ = 2048;
constexpr int HID = 1024;
constexpr int NHEAD = 16;
constexpr int HDIM = 64;
constexpr int MROWS = BATCH * SEQ;          // 4096
constexpr int QKV_LD = 3 * HID;             // 3072
constexpr int BIAS_LD = 2 * 1024 + 1;       // 2049
constexpr size_t BIAS_HSTRIDE = (size_t)BIAS_LD * BIAS_LD;

// 16B payload, 4B-aligned (bias rows have stride 2049 floats -> not 16B aligned)
struct f4u { float v[4]; };

__device__ __forceinline__ u16 f2bf(float f) {
    u32 u = __builtin_bit_cast(u32, f);
    u32 r = u + 0x7fffu + ((u >> 16) & 1u);   // RNE
    return (u16)(r >> 16);
}
__device__ __forceinline__ u16 f2bf_fast(float f) {  // round-to-nearest (no tie fix) — P weights only
    return (u16)((__builtin_bit_cast(u32, f) + 0x8000u) >> 16);
}
__device__ __forceinline__ float bf2f(u16 h) {
    return __builtin_bit_cast(float, (u32)h << 16);
}

// async global->LDS, 16B per lane. LDS dst = wave-uniform base + lane*16.
__device__ __forceinline__ void gld16(const void* g, void* lds_base) {
    __builtin_amdgcn_global_load_lds(
        (const __attribute__((address_space(1))) u32*)(uintptr_t)g,
        (__attribute__((address_space(3))) u32*)(u32)(uintptr_t)lds_base,
        16, 0, 0);
}

// swizzled LDS chunk offsets (16B chunks): position c in row r holds chunk c^(r&7); 128B rows
__device__ __forceinline__ int swoff8(int row, int chunk)  { return (row * 8  + (chunk ^ (row & 7)))  << 4; }

__device__ __forceinline__ float2 blockreduce2(float a, float b) {
    #pragma unroll
    for (int m = 1; m < 64; m <<= 1) {
        a += __shfl_xor(a, m, 64);
        b += __shfl_xor(b, m, 64);
    }
    __shared__ float la[4], lb[4];
    int w = threadIdx.x >> 6;
    if ((threadIdx.x & 63) == 0) { la[w] = a; lb[w] = b; }
    __syncthreads();
    a = la[0] + la[1] + la[2] + la[3];
    b = lb[0] + lb[1] + lb[2] + lb[3];
    __syncthreads();
    return make_float2(a, b);
}

// ---------------- weight transpose + fp32 -> bf16 (scaled):  W[K,N] -> Wt[N,K] ----------------
__global__ __launch_bounds__(256) void k_wt(const float* __restrict__ W, u16* __restrict__ Wt,
                                            int K, int N, float scale) {
    __shared__ float t[32][33];
    int n0 = blockIdx.x * 32, k0 = blockIdx.y * 32;
    int tx = threadIdx.x & 31, ty = threadIdx.x >> 5;  // 32 x 8
    #pragma unroll
    for (int i = 0; i < 32; i += 8) t[ty + i][tx] = W[(size_t)(k0 + ty + i) * N + n0 + tx];
    __syncthreads();
    #pragma unroll
    for (int i = 0; i < 32; i += 8) Wt[(size_t)(n0 + ty + i) * K + k0 + tx] = f2bf(t[tx][ty + i] * scale);
}

// ---------------- concat bias for fused QKV (q scaled by 1/8) ----------------
__global__ __launch_bounds__(256) void k_bcat(const float* __restrict__ bq, const float* __restrict__ bk,
                                              const float* __restrict__ bv, float* __restrict__ o) {
    int n = blockIdx.x * 256 + threadIdx.x;
    float v = (n < 1024) ? bq[n] * 0.125f : (n < 2048 ? bk[n - 1024] : bv[n - 2048]);
    o[n] = v;
}

// ---------------- pe (Linear(1->H)+LN) + add + LN -> x (bf16) ----------------
__global__ __launch_bounds__(256) void k_prenorm(const float* __restrict__ hidden,
        const float* __restrict__ pe_w, const float* __restrict__ pe_b,
        const float* __restrict__ pe_g, const float* __restrict__ pe_beta,
        const float* __restrict__ ng, const float* __restrict__ nb, u16* __restrict__ xbf) {
    int row = blockIdx.x;                 // b*SEQ + s
    int s = row & (SEQ - 1);
    float pos = ((float)s - 1024.0f) * (1.0f / 1024.0f);
    int t = threadIdx.x, hh = t * 4;
    float4 pw = *(const float4*)(pe_w + hh);
    float4 pb = *(const float4*)(pe_b + hh);
    float v[4] = { pos * pw.x + pb.x, pos * pw.y + pb.y, pos * pw.z + pb.z, pos * pw.w + pb.w };
    float s1 = 0.f, s2 = 0.f;
    #pragma unroll
    for (int i = 0; i < 4; i++) { s1 += v[i]; s2 += v[i] * v[i]; }
    float2 red = blockreduce2(s1, s2);
    float mean = red.x * (1.f / HID);
    float var  = red.y * (1.f / HID) - mean * mean;
    float rstd = rsqrtf(var + 1e-5f);
    float4 pg = *(const float4*)(pe_g + hh);
    float4 pbe = *(const float4*)(pe_beta + hh);
    float4 hv = *(const float4*)(hidden + (size_t)row * HID + hh);
    v[0] = hv.x + (v[0] - mean) * rstd * pg.x + pbe.x;
    v[1] = hv.y + (v[1] - mean) * rstd * pg.y + pbe.y;
    v[2] = hv.z + (v[2] - mean) * rstd * pg.z + pbe.z;
    v[3] = hv.w + (v[3] - mean) * rstd * pg.w + pbe.w;
    s1 = 0.f; s2 = 0.f;
    #pragma unroll
    for (int i = 0; i < 4; i++) { s1 += v[i]; s2 += v[i] * v[i]; }
    red = blockreduce2(s1, s2);
    mean = red.x * (1.f / HID);
    var  = red.y * (1.f / HID) - mean * mean;
    rstd = rsqrtf(var + 1e-5f);
    float4 gg = *(const float4*)(ng + hh);
    float4 bb = *(const float4*)(nb + hh);
    ushort4 o;
    o.x = f2bf((v[0] - mean) * rstd * gg.x + bb.x);
    o.y = f2bf((v[1] - mean) * rstd * gg.y + bb.y);
    o.z = f2bf((v[2] - mean) * rstd * gg.z + bb.z);
    o.w = f2bf((v[3] - mean) * rstd * gg.w + bb.w);
    *(ushort4*)(xbf + (size_t)row * HID + hh) = o;
}

// ---------------- LN + ReLU: bf16 [rows][2048] -> bf16, 8 elems/thread ----------------
__global__ __launch_bounds__(256) void k_ln_relu(const u16* __restrict__ Z,
        const float* __restrict__ g, const float* __restrict__ be, u16* __restrict__ Y) {
    const int N = 2048;
    int row = blockIdx.x, t = threadIdx.x, base = t * 8;
    union { uint4 q; u16 h[8]; } u;
    u.q = *(const uint4*)(Z + (size_t)row * N + base);
    float v[8];
    float s1 = 0.f, s2 = 0.f;
    #pragma unroll
    for (int i = 0; i < 8; i++) { v[i] = bf2f(u.h[i]); s1 += v[i]; s2 += v[i] * v[i]; }
    float2 red = blockreduce2(s1, s2);
    float mean = red.x * (1.f / N);
    float var  = red.y * (1.f / N) - mean * mean;
    float rstd = rsqrtf(var + 1e-5f);
    float4 g0 = *(const float4*)(g + base), g1 = *(const float4*)(g + base + 4);
    float4 b0 = *(const float4*)(be + base), b1 = *(const float4*)(be + base + 4);
    float gg[8] = { g0.x, g0.y, g0.z, g0.w, g1.x, g1.y, g1.z, g1.w };
    float bb[8] = { b0.x, b0.y, b0.z, b0.w, b1.x, b1.y, b1.z, b1.w };
    union { uint4 q; u16 h[8]; } o;
    #pragma unroll
    for (int i = 0; i < 8; i++) o.h[i] = f2bf(fmaxf((v[i] - mean) * rstd * gg[i] + bb[i], 0.f));
    *(uint4*)(Y + (size_t)row * N + base) = o.q;
}

// ---------------- V transpose: qkv[b*S][3072] (V block) -> [b][h][d][S] (bf16) ----------------
__global__ __launch_bounds__(256) void k_vtrans(const u16* __restrict__ QKV, u16* __restrict__ Vt) {
    __shared__ u16 t[64][68];
    int s0 = blockIdx.x * 64, h = blockIdx.y, b = blockIdx.z;
    int x = threadIdx.x & 63, y = threadIdx.x >> 6;
    #pragma unroll
    for (int i = 0; i < 64; i += 4) {
        int r = i + y;
        t[r][x] = QKV[(size_t)(b * SEQ + s0 + r) * QKV_LD + 2048 + h * HDIM + x];
    }
    __syncthreads();
    size_t ob = (size_t)(b * NHEAD + h) * HDIM;
    #pragma unroll
    for (int i = 0; i < 64; i += 4) {
        int d = i + y;
        Vt[(ob + d) * SEQ + s0 + x] = t[x][d];
    }
}

// ---------------- bf16 MFMA GEMM: C[M,N] = A[M,K] @ Bt[N,K]^T + bias ----------------
// 128x128 tile, BK=64, DOUBLE-BUFFERED async global_load_lds staging:
// one barrier/iter, next tile's DMA issued right after the barrier (latency hidden under compute).
template <int OUT_BF16>
__global__ __launch_bounds__(256, 2) void k_gemm(const u16* __restrict__ A, const u16* __restrict__ Bt,
        const float* __restrict__ bias, void* __restrict__ C, int N, int K) {
    __shared__ __align__(16) u16 lA[2][128 * 64];
    __shared__ __align__(16) u16 lB[2][128 * 64];
    const int m0 = blockIdx.x * 128, n0 = blockIdx.y * 128;
    const int tid = threadIdx.x, wave = tid >> 6, lane = tid & 63;
    const int wr = wave >> 1, wc = wave & 1, q4 = lane >> 4, ml = lane & 15;
    const int srow = wave * 8 + (lane >> 3);
    const int sqc  = (lane & 7) ^ (lane >> 3);

    auto stage = [&](int p, int k0) {
        #pragma unroll
        for (int it = 0; it < 4; it++) {
            int r = it * 32 + srow;
            gld16(A  + (size_t)(m0 + r) * K + k0 + sqc * 8, (char*)lA[p] + (it * 32 + wave * 8) * 128);
            gld16(Bt + (size_t)(n0 + r) * K + k0 + sqc * 8, (char*)lB[p] + (it * 32 + wave * 8) * 128);
        }
    };

    v4f acc[4][4];
    v4f zz = {0.f, 0.f, 0.f, 0.f};
    #pragma unroll
    for (int i = 0; i < 4; i++)
        #pragma unroll
        for (int j = 0; j < 4; j++) acc[i][j] = zz;

    stage(0, 0);
    int p = 0;
    for (int k0 = 0; k0 < K; k0 += 64) {
        __syncthreads();                       // drains stage(p); compiler emits vmcnt(0) here
        int kn = (k0 + 64 < K) ? k0 + 64 : k0; // clamped re-stage on last iter (harmless)
        stage(p ^ 1, kn);
        char* lAc = (char*)lA[p];
        char* lBc = (char*)lB[p];
        #pragma unroll
        for (int kk = 0; kk < 2; kk++) {
            v8bf af[4], bfv[4];
            #pragma unroll
            for (int i = 0; i < 4; i++) af[i] = *(const v8bf*)(lAc + swoff8(wr * 64 + i * 16 + ml, kk * 4 + q4));
            #pragma unroll
            for (int j = 0; j < 4; j++) bfv[j] = *(const v8bf*)(lBc + swoff8(wc * 64 + j * 16 + ml, kk * 4 + q4));
            #pragma unroll
            for (int i = 0; i < 4; i++)
                #pragma unroll
                for (int j = 0; j < 4; j++)
                    acc[i][j] = __builtin_amdgcn_mfma_f32_16x16x32_bf16(af[i], bfv[j], acc[i][j], 0, 0, 0);
        }
        p ^= 1;
    }
    #pragma unroll
    for (int i = 0; i < 4; i++) {
        int rb = m0 + wr * 64 + i * 16 + q4 * 4;
        #pragma unroll
        for (int j = 0; j < 4; j++) {
            int col = n0 + wc * 64 + j * 16 + ml;
            float bv = bias[col];
            #pragma unroll
            for (int r = 0; r < 4; r++) {
                float val = acc[i][j][r] + bv;
                if (OUT_BF16) ((u16*)C)[(size_t)(rb + r) * N + col] = f2bf(val);
                else          ((float*)C)[(size_t)(rb + r) * N + col] = val;
            }
        }
    }
}

// ---------------- flash attention, S^T formulation, block-shared dbuf K/V staging ----------------
// grid (b=2, qt=16, h=16) = 512 blocks (2/CU). Block = 128 q (4 waves x 32 q), k-tile 64.
// K-tile [64k][64d] and V^T-tile [64d][64k] staged once per block via global_load_lds into
// double-buffered LDS (prefetch across the single per-iter barrier). Bias: 8 dwordx4/wave/iter,
// prefetched one iter ahead. P roundtrip via per-wave padded LDS. All frags 16x16x32 (verified).
__global__ __launch_bounds__(256, 2) void k_attn(const u16* __restrict__ QKV,
        const u16* __restrict__ Vtm, const float* __restrict__ bias, u16* __restrict__ ctx) {
    __shared__ __align__(16) u16 lK[2][64 * 64];     // [k][d] swizzled, 8KB/buf
    __shared__ __align__(16) u16 lV[2][64 * 64];     // [d][k] swizzled, 8KB/buf
    __shared__ __align__(16) u16 lP[4][32 * 72];     // per-wave P^T [q][k], row stride 144B
    const int b = blockIdx.x, qt = blockIdx.y, h = blockIdx.z;
    const int tid = threadIdx.x, wave = tid >> 6, lane = tid & 63;
    const int q4 = lane >> 4, ml = lane & 15;
    char* lPc = (char*)lP[wave];
    const int qbase = qt * 128 + wave * 32;
    const int srow = (lane >> 3);                    // 0..7 within an 8-row staging group

    const u16* Qb = QKV + (size_t)(b * SEQ) * QKV_LD + h * HDIM;
    const u16* Kb = QKV + (size_t)(b * SEQ) * QKV_LD + 1024 + h * HDIM;
    const u16* Vb = Vtm + (size_t)(b * NHEAD + h) * HDIM * SEQ;
    const float* brow0 = bias + (size_t)h * BIAS_HSTRIDE + (size_t)(qbase + ml) * BIAS_LD;
    const float* brow1 = brow0 + (size_t)16 * BIAS_LD;

    // stage K[k0+r][d] and V^T[r][k0+..] for rows r in wave*16..wave*16+15 (2 gld16 each)
    auto stage = [&](int p, int k0) {
        #pragma unroll
        for (int it = 0; it < 2; it++) {
            int r = wave * 16 + it * 8 + srow;
            int c = (lane & 7) ^ (r & 7);
            gld16(Kb + (size_t)(k0 + r) * QKV_LD + c * 8, (char*)lK[p] + (wave * 16 + it * 8) * 128);
            gld16(Vb + (size_t)r * SEQ + k0 + c * 8,      (char*)lV[p] + (wave * 16 + it * 8) * 128);
        }
    };

    // Q B-frags (loop-invariant): qf[qs][dseg] = Q[q=qbase+qs*16+ml][dseg*32 + q4*8 ..+8]
    v8bf qf[2][2];
    #pragma unroll
    for (int qs = 0; qs < 2; qs++)
        #pragma unroll
        for (int ds = 0; ds < 2; ds++)
            qf[qs][ds] = *(const v8bf*)(Qb + (size_t)(qbase + qs * 16 + ml) * QKV_LD + ds * 32 + q4 * 8);

    float mr[2] = { -1e30f, -1e30f }, lr[2] = { 0.f, 0.f };
    v4f o[4][2];                                     // O^T: [dt][qs], col q, rows d=dt*16+q4*4+r
    v4f zz = {0.f, 0.f, 0.f, 0.f};
    #pragma unroll
    for (int dt = 0; dt < 4; dt++)
        #pragma unroll
        for (int qs = 0; qs < 2; qs++) o[dt][qs] = zz;

    // bias prefetch for kt=0
    f4u bv[2][4];
    #pragma unroll
    for (int jt = 0; jt < 4; jt++) {
        bv[0][jt] = *(const f4u*)(brow0 + jt * 16 + q4 * 4);
        bv[1][jt] = *(const f4u*)(brow1 + jt * 16 + q4 * 4);
    }

    stage(0, 0);
    int p = 0;
    for (int kt = 0; kt < SEQ / 64; ++kt) {
        const int k0 = kt * 64;
        __syncthreads();                             // drains stage(p) DMA + protects buffers
        const int kn = (kt < SEQ / 64 - 1) ? k0 + 64 : k0;
        stage(p ^ 1, kn);
        // bias prefetch for next iter (latency covered by this iter's compute)
        f4u bn[2][4];
        #pragma unroll
        for (int jt = 0; jt < 4; jt++) {
            bn[0][jt] = *(const f4u*)(brow0 + kn + jt * 16 + q4 * 4);
            bn[1][jt] = *(const f4u*)(brow1 + kn + jt * 16 + q4 * 4);
        }
        char* lKc = (char*)lK[p];
        char* lVc = (char*)lV[p];

        // S^T = K·Q^T : sa[jt][qs], rows k = jt*16+q4*4+r, col q = qs*16+ml
        v4f sa[4][2];
        #pragma unroll
        for (int jt = 0; jt < 4; jt++) {
            v8bf kf0 = *(const v8bf*)(lKc + swoff8(jt * 16 + ml, q4));
            v8bf kf1 = *(const v8bf*)(lKc + swoff8(jt * 16 + ml, 4 + q4));
            #pragma unroll
            for (int qs = 0; qs < 2; qs++) {
                sa[jt][qs] = __builtin_amdgcn_mfma_f32_16x16x32_bf16(kf0, qf[qs][0], zz, 0, 0, 0);
                sa[jt][qs] = __builtin_amdgcn_mfma_f32_16x16x32_bf16(kf1, qf[qs][1], sa[jt][qs], 0, 0, 0);
            }
        }
        // bias add + online softmax per qs
        #pragma unroll
        for (int qs = 0; qs < 2; qs++) {
            float mx = -1e30f;
            #pragma unroll
            for (int jt = 0; jt < 4; jt++)
                #pragma unroll
                for (int r = 0; r < 4; r++) { sa[jt][qs][r] += bv[qs][jt].v[r]; mx = fmaxf(mx, sa[jt][qs][r]); }
            mx = fmaxf(mx, __shfl_xor(mx, 16, 64));
            mx = fmaxf(mx, __shfl_xor(mx, 32, 64));
            float mnew = fmaxf(mr[qs], mx);
            float alpha = __expf(mr[qs] - mnew);
            mr[qs] = mnew;
            float rs = 0.f;
            #pragma unroll
            for (int jt = 0; jt < 4; jt++)
                #pragma unroll
                for (int r = 0; r < 4; r++) {
                    float pe = __expf(sa[jt][qs][r] - mnew);
                    sa[jt][qs][r] = pe;
                    rs += pe;
                }
            rs += __shfl_xor(rs, 16, 64);
            rs += __shfl_xor(rs, 32, 64);
            lr[qs] = lr[qs] * alpha + rs;
            #pragma unroll
            for (int dt = 0; dt < 4; dt++) o[dt][qs] *= alpha;
            // P^T -> per-wave LDS [q][k]: 8B per (jt): k = jt*16 + q4*4 ..+4
            #pragma unroll
            for (int jt = 0; jt < 4; jt++) {
                uint2 pk;
                pk.x = (u32)f2bf_fast(sa[jt][qs][0]) | ((u32)f2bf_fast(sa[jt][qs][1]) << 16);
                pk.y = (u32)f2bf_fast(sa[jt][qs][2]) | ((u32)f2bf_fast(sa[jt][qs][3]) << 16);
                *(uint2*)(lPc + (qs * 16 + ml) * 144 + jt * 32 + q4 * 8) = pk;
            }
        }
        // O^T += V^T·P^T : A = V^T[16d][32k] from lV, B = P^T[32k][16q] from lP
        #pragma unroll
        for (int ks = 0; ks < 2; ks++) {
            v8bf pf[2];
            #pragma unroll
            for (int qs = 0; qs < 2; qs++)
                pf[qs] = *(const v8bf*)(lPc + (qs * 16 + ml) * 144 + ks * 64 + q4 * 16);
            #pragma unroll
            for (int dt = 0; dt < 4; dt++) {
                v8bf vf = *(const v8bf*)(lVc + swoff8(dt * 16 + ml, ks * 4 + q4));
                #pragma unroll
                for (int qs = 0; qs < 2; qs++)
                    o[dt][qs] = __builtin_amdgcn_mfma_f32_16x16x32_bf16(vf, pf[qs], o[dt][qs], 0, 0, 0);
            }
        }
        #pragma unroll
        for (int jt = 0; jt < 4; jt++) { bv[0][jt] = bn[0][jt]; bv[1][jt] = bn[1][jt]; }
        p ^= 1;
    }
    // epilogue: O^T[d][q]/l -> ctx[q][h*64+d], 8B stores
    #pragma unroll
    for (int qs = 0; qs < 2; qs++) {
        float inv = 1.0f / lr[qs];
        size_t rowb = (size_t)(b * SEQ + qbase + qs * 16 + ml) * HID + h * HDIM + q4 * 4;
        #pragma unroll
        for (int dt = 0; dt < 4; dt++) {
            ushort4 st;
            st.x = f2bf(o[dt][qs][0] * inv);
            st.y = f2bf(o[dt][qs][1] * inv);
            st.z = f2bf(o[dt][qs][2] * inv);
            st.w = f2bf(o[dt][qs][3] * inv);
            *(ushort4*)(ctx + rowb + dt * 16) = st;
        }
    }
}

extern "C" void kernel_launch(void* const* d_in, const int* in_sizes, int n_in,
                              void* d_out, int out_size, void* d_ws, size_t ws_size,
                              hipStream_t stream) {
    const float* hidden = (const float*)d_in[0];
    const float* wbias  = (const float*)d_in[1];
    const float* pe_w   = (const float*)d_in[2];
    const float* pe_b   = (const float*)d_in[3];
    const float* pe_g   = (const float*)d_in[4];
    const float* pe_be  = (const float*)d_in[5];
    const float* ng     = (const float*)d_in[6];
    const float* nb     = (const float*)d_in[7];
    const float* Wq = (const float*)d_in[8];  const float* bq = (const float*)d_in[9];
    const float* Wk = (const float*)d_in[10]; const float* bk = (const float*)d_in[11];
    const float* Wv = (const float*)d_in[12]; const float* bv = (const float*)d_in[13];
    const float* W1 = (const float*)d_in[14]; const float* b1 = (const float*)d_in[15];
    const float* g1 = (const float*)d_in[16]; const float* be1 = (const float*)d_in[17];
    const float* W2 = (const float*)d_in[18]; const float* b2 = (const float*)d_in[19];
    const float* g2 = (const float*)d_in[20]; const float* be2 = (const float*)d_in[21];
    const float* W3 = (const float*)d_in[22]; const float* b3 = (const float*)d_in[23];
    const float* g3 = (const float*)d_in[24]; const float* be3 = (const float*)d_in[25];
    const float* W4 = (const float*)d_in[26]; const float* b4 = (const float*)d_in[27];

    char* ws = (char*)d_ws;
    size_t off = 0;
    auto alloc = [&](size_t bytes) {
        char* p = ws + off;
        off += (bytes + 1023) & ~(size_t)1023;
        return p;
    };
    u16* wqkvt = (u16*)alloc((size_t)3072 * 1024 * 2);
    u16* w1t = (u16*)alloc((size_t)2048 * 1024 * 2);
    u16* w2t = (u16*)alloc((size_t)2048 * 2048 * 2);
    u16* w3t = (u16*)alloc((size_t)2048 * 2048 * 2);
    u16* w4t = (u16*)alloc((size_t)1024 * 2048 * 2);
    float* bqkv = (float*)alloc((size_t)3072 * 4);
    u16* xbf = (u16*)alloc((size_t)MROWS * HID * 2);
    u16* qkv = (u16*)alloc((size_t)MROWS * QKV_LD * 2);
    u16* vtb = (u16*)alloc((size_t)MROWS * HID * 2);
    u16* ctx = (u16*)alloc((size_t)MROWS * HID * 2);
    u16* zb  = (u16*)alloc((size_t)MROWS * 2048 * 2);
    u16* ya  = (u16*)alloc((size_t)MROWS * 2048 * 2);
    u16* yb  = (u16*)alloc((size_t)MROWS * 2048 * 2);

    dim3 blk(256);
    // weight transposes (fp32 -> bf16 [N,K]); 1/8 attention scale folded into Wq
    k_wt<<<dim3(32, 32), blk, 0, stream>>>(Wq, wqkvt, 1024, 1024, 0.125f);
    k_wt<<<dim3(32, 32), blk, 0, stream>>>(Wk, wqkvt + (size_t)1024 * 1024, 1024, 1024, 1.0f);
    k_wt<<<dim3(32, 32), blk, 0, stream>>>(Wv, wqkvt + (size_t)2048 * 1024, 1024, 1024, 1.0f);
    k_wt<<<dim3(64, 32), blk, 0, stream>>>(W1, w1t, 1024, 2048, 1.0f);
    k_wt<<<dim3(64, 64), blk, 0, stream>>>(W2, w2t, 2048, 2048, 1.0f);
    k_wt<<<dim3(64, 64), blk, 0, stream>>>(W3, w3t, 2048, 2048, 1.0f);
    k_wt<<<dim3(32, 64), blk, 0, stream>>>(W4, w4t, 2048, 1024, 1.0f);
    k_bcat<<<dim3(12), blk, 0, stream>>>(bq, bk, bv, bqkv);
    // x = LN(hidden + LN(pos*pe_w + pe_b))
    k_prenorm<<<MROWS, blk, 0, stream>>>(hidden, pe_w, pe_b, pe_g, pe_be, ng, nb, xbf);
    // fused QKV projection -> qkv [4096][3072]
    k_gemm<1><<<dim3(32, 24), blk, 0, stream>>>(xbf, wqkvt, bqkv, qkv, QKV_LD, 1024);
    // V -> [b][h][d][s]
    k_vtrans<<<dim3(32, 16, 2), blk, 0, stream>>>(qkv, vtb);
    // fused attention
    k_attn<<<dim3(2, 16, 16), blk, 0, stream>>>(qkv, vtb, wbias, ctx);
    // out_proj MLP (bf16 intermediates)
    k_gemm<1><<<dim3(32, 16), blk, 0, stream>>>(ctx, w1t, b1, zb, 2048, 1024);
    k_ln_relu<<<MROWS, blk, 0, stream>>>(zb, g1, be1, ya);
    k_gemm<1><<<dim3(32, 16), blk, 0, stream>>>(ya, w2t, b2, zb, 2048, 2048);
    k_ln_relu<<<MROWS, blk, 0, stream>>>(zb, g2, be2, yb);
    k_gemm<1><<<dim3(32, 16), blk, 0, stream>>>(yb, w3t, b3, zb, 2048, 2048);
    k_ln_relu<<<MROWS, blk, 0, stream>>>(zb, g3, be3, ya);
    k_gemm<0><<<dim3(32, 8), blk, 0, stream>>>(ya, w4t, b4, (float*)d_out, 1024, 2048);
}